// Round 14
// baseline (778.129 us; speedup 1.0000x reference)
//
#include <hip/hip_runtime.h>
#include <math.h>

#define H 256
#define G3 768        // 3*H
#define BB 512
#define AA 4
#define EE 10
#define RP (BB*AA*EE) // 20480 physical rows
#define RA (BB*AA)    // 2048 action rows
#define TT 10
#define NMV 2
#define STEPSC 0.05f
#define DST 260       // act LDS row stride (floats)
#define FAB 128       // fused action blocks (pool + GRU_a + fc_a + m1 + m2)
#define COMB 2560     // combined fc+gru: 320 row-tiles x 8 col-groups

typedef __attribute__((ext_vector_type(8))) short short8;
typedef __attribute__((ext_vector_type(8))) _Float16 half8;
typedef __attribute__((ext_vector_type(4))) float f32x4;

#if defined(__has_builtin)
#  if __has_builtin(__builtin_amdgcn_global_load_lds)
#    define HAS_GLL 1
#  endif
#  if __has_builtin(__builtin_nontemporal_load)
#    define HAS_NT 1
#  endif
#endif

__device__ __forceinline__ float sigmoid_(float x){ return 1.f/(1.f + __expf(-x)); }
__device__ __forceinline__ float tanh_(float x){
    float ax = fabsf(x);
    float e  = __expf(-2.f*ax);
    float t  = (1.f - e)/(1.f + e);
    return copysignf(t, x);
}
__device__ __forceinline__ float elu_(float x){ return x > 0.f ? x : (__expf(x) - 1.f); }

#define MFMA16(A,B,C) __builtin_amdgcn_mfma_f32_16x16x32_f16(A,B,C,0,0,0)

__device__ __forceinline__ void cp16(const void* g, void* l) {
#ifdef HAS_GLL
    __builtin_amdgcn_global_load_lds(
        (const __attribute__((address_space(1))) unsigned int*)g,
        (__attribute__((address_space(3))) unsigned int*)l, 16, 0, 0);
#else
    *(short8*)l = *(const short8*)g;
#endif
}

__device__ __forceinline__ half8 ntload_h8(const _Float16* p) {
#ifdef HAS_NT
    return __builtin_nontemporal_load((const half8*)p);
#else
    return *(const half8*)p;
#endif
}
__device__ __forceinline__ void ntstore_h(_Float16* p, _Float16 v) {
#ifdef HAS_NT
    __builtin_nontemporal_store(v, p);
#else
    *p = v;
#endif
}

// ---------------------------------------------------------------------------
// fp32 weight [Nout][ldsrc] -> fp16 in MFMA B-fragment order.
// i = ((chunk*8 + kc)*64 + lane)*8 + j ; row = chunk*16+(lane&15),
// k = kc*32 + (lane>>4)*8 + j.  Chunk = 16 output cols x 256 k = 4096 halfs.
// ---------------------------------------------------------------------------
__global__ void k_splitw(const float* __restrict__ src, _Float16* __restrict__ dst,
                         int n, int ldsrc)
{
    int i = blockIdx.x*256 + threadIdx.x;
    if (i < n) {
        int j  = i & 7;
        int l  = (i >> 3) & 63;
        int kc = (i >> 9) & 7;
        int c  = i >> 12;
        int row = c*16 + (l & 15);
        int k   = kc*32 + (l >> 4)*8 + j;
        dst[i] = (_Float16)src[(size_t)row*ldsrc + k];
    }
}

// gia[ra][k] = b_ih_a[k] + sum_{j<3} goals[ra][j]*W_ih_a[k][256+j]  (fp16 out)
__global__ void k_gia_goal(const float* __restrict__ goals,
                           const float* __restrict__ Wiha,
                           const float* __restrict__ biha,
                           _Float16* __restrict__ out)
{
    int idx = blockIdx.x*256 + threadIdx.x;
    int ra = idx / G3, k = idx % G3;
    float g0 = goals[ra*3+0], g1 = goals[ra*3+1], g2 = goals[ra*3+2];
    const float* w = Wiha + (size_t)k*259 + 256;
    out[idx] = (_Float16)(biha[k] + g0*w[0] + g1*w[1] + g2*w[2]);
}

// fp32 -> fp16 convert (state init)
__global__ void k_cvt(const float* __restrict__ src, _Float16* __restrict__ dst, int n)
{
    int i = blockIdx.x*256 + threadIdx.x;
    if (i < n) dst[i] = (_Float16)src[i];
}

// ---------------------------------------------------------------------------
// FUSED STEP KERNEL — 3-stage pipeline across launches (12 launches total).
//   [0,FAB):    fused action chain act_t: pool + GRU_a(+gi) + fc_a + m1 + m2.
//               ha ping-pong (r12-proven); proca/m1o live in LDS only.
//   [FAB,+COMB): combined fc(fc_t)+gru(gru_t): shared A-frags, 8 col-groups,
//               2 gru slices + 1 fc slice per block (r13-proven).
// ---------------------------------------------------------------------------
__global__ __launch_bounds__(256, 2)
void k_step(int gru_t, int fc_t, int act_t,
            _Float16* __restrict__ hp0, _Float16* __restrict__ hp1,
            _Float16* __restrict__ proc0, _Float16* __restrict__ proc1,
            _Float16* __restrict__ ha0, _Float16* __restrict__ ha1,
            const _Float16* __restrict__ wWhh, const _Float16* __restrict__ wWfc,
            const _Float16* __restrict__ wWhha, const _Float16* __restrict__ wWiha,
            const _Float16* __restrict__ wWfca, const _Float16* __restrict__ wWm1,
            const _Float16* __restrict__ gia,
            const float* __restrict__ obs, const float* __restrict__ phys,
            const float* __restrict__ Wih, const float* __restrict__ bih,
            const float* __restrict__ bhh, const float* __restrict__ bfcp,
            const float* __restrict__ bhha, const float* __restrict__ bfca,
            const float* __restrict__ bm1,
            const float* __restrict__ Wm2, const float* __restrict__ bm2,
            float* __restrict__ out)
{
    __shared__ char smem[24576];
    int b = blockIdx.x;
    const int tid = threadIdx.x;
    const int wv = tid >> 6, lane = tid & 63;
    const int quad = lane >> 4, l16 = lane & 15;

    // ===================== FUSED ACTION ROLE =====================
    if (b < FAB) {
        if (act_t < 0) return;
        float* D = (float*)smem;
        const _Float16* proc = (act_t & 1) ? proc1 : proc0;
        const _Float16* hain = (act_t & 1) ? ha1 : ha0;
        _Float16*      haout = (act_t & 1) ? ha0 : ha1;
        const int ra0 = b*16;

        // pool: feat = max_e proc (half8-vectorized, nontemporal)
        for (int i = tid; i < 16*32; i += 256) {
            int r = i >> 5, cg = (i & 31)*8;
            const _Float16* p = proc + ((size_t)(ra0 + r)*EE)*H + cg;
            half8 v = ntload_h8(p);
            float m[8];
            #pragma unroll
            for (int j = 0; j < 8; j++) m[j] = (float)v[j];
            #pragma unroll
            for (int e = 1; e < EE; e++) {
                half8 u = ntload_h8(p + (size_t)e*H);
                #pragma unroll
                for (int j = 0; j < 8; j++) m[j] = fmaxf(m[j], (float)u[j]);
            }
            #pragma unroll
            for (int j = 0; j < 8; j++) D[r*DST + cg + j] = m[j];
        }
        __syncthreads();

        half8 Fh[8], Hh[8];
        #pragma unroll
        for (int kc = 0; kc < 8; kc++) {
            const float* fp = &D[l16*DST + quad*8 + kc*32];
            #pragma unroll
            for (int j = 0; j < 8; j++) Fh[kc][j] = (_Float16)fp[j];
            Hh[kc] = *(const half8*)(hain + (size_t)(ra0 + l16)*H + quad*8 + kc*32);
        }

        // GRU_a (gh + gi fused), 2 passes x 2 col-chunks per wave -> haout
        #pragma unroll
        for (int p = 0; p < 2; p++) {
            f32x4 gh[3][2], gx[3][2];
            #pragma unroll
            for (int g = 0; g < 3; g++)
                #pragma unroll
                for (int ch = 0; ch < 2; ch++) {
                    gh[g][ch] = (f32x4){0.f,0.f,0.f,0.f};
                    gx[g][ch] = (f32x4){0.f,0.f,0.f,0.f};
                }
            #pragma unroll
            for (int kc = 0; kc < 8; kc++)
                #pragma unroll
                for (int ch = 0; ch < 2; ch++)
                    #pragma unroll
                    for (int g = 0; g < 3; g++) {
                        const size_t cg = (size_t)(g*16 + wv*4 + p*2 + ch);
                        half8 bh = *(const half8*)(wWhha + (cg*8+kc)*512 + lane*8);
                        half8 bx = *(const half8*)(wWiha + (cg*8+kc)*512 + lane*8);
                        gh[g][ch] = MFMA16(Hh[kc], bh, gh[g][ch]);
                        gx[g][ch] = MFMA16(Fh[kc], bx, gx[g][ch]);
                    }
            #pragma unroll
            for (int ch = 0; ch < 2; ch++) {
                const int c = wv*64 + (p*2+ch)*16 + l16;
                const float br = bhha[c], bz = bhha[256+c], bn = bhha[512+c];
                #pragma unroll
                for (int reg = 0; reg < 4; reg++) {
                    const int r = quad*4 + reg;
                    const _Float16* gp = gia + (size_t)(ra0 + r)*G3;
                    float rg = sigmoid_((float)gp[c]     + gx[0][ch][reg] + gh[0][ch][reg] + br);
                    float z  = sigmoid_((float)gp[256+c] + gx[1][ch][reg] + gh[1][ch][reg] + bz);
                    float n  = tanh_((float)gp[512+c] + gx[2][ch][reg] + rg*(gh[2][ch][reg] + bn));
                    size_t idx = (size_t)(ra0 + r)*H + c;
                    float hprev = (float)hain[idx];
                    haout[idx] = (_Float16)((1.f - z)*n + z*hprev);
                }
            }
        }
        __threadfence_block();
        __syncthreads();   // (1) haout visible; D(feat) frag reads done

        // fc_a: proca = elu(h_a' @ Wfca^T + bfca) -> D
        #pragma unroll
        for (int kc = 0; kc < 8; kc++)
            Hh[kc] = *(const half8*)(haout + (size_t)(ra0 + l16)*H + quad*8 + kc*32);
        {
            f32x4 ac[4];
            #pragma unroll
            for (int ch = 0; ch < 4; ch++) ac[ch] = (f32x4){0.f,0.f,0.f,0.f};
            #pragma unroll
            for (int kc = 0; kc < 8; kc++)
                #pragma unroll
                for (int ch = 0; ch < 4; ch++) {
                    half8 w = *(const half8*)(wWfca + ((size_t)(wv*4+ch)*8+kc)*512 + lane*8);
                    ac[ch] = MFMA16(Hh[kc], w, ac[ch]);
                }
            #pragma unroll
            for (int ch = 0; ch < 4; ch++) {
                const int c = wv*64 + ch*16 + l16;
                const float bs = bfca[c];
                #pragma unroll
                for (int reg = 0; reg < 4; reg++)
                    D[(quad*4+reg)*DST + c] = elu_(ac[ch][reg] + bs);
            }
        }
        __syncthreads();   // (2) proca in D

        // m1: frags of proca
        #pragma unroll
        for (int kc = 0; kc < 8; kc++) {
            const float* fp = &D[l16*DST + quad*8 + kc*32];
            #pragma unroll
            for (int j = 0; j < 8; j++) Fh[kc][j] = (_Float16)fp[j];
        }
        __syncthreads();   // (3) reads done before overwrite
        {
            f32x4 ac[4];
            #pragma unroll
            for (int ch = 0; ch < 4; ch++) ac[ch] = (f32x4){0.f,0.f,0.f,0.f};
            #pragma unroll
            for (int kc = 0; kc < 8; kc++)
                #pragma unroll
                for (int ch = 0; ch < 4; ch++) {
                    half8 w = *(const half8*)(wWm1 + ((size_t)(wv*4+ch)*8+kc)*512 + lane*8);
                    ac[ch] = MFMA16(Fh[kc], w, ac[ch]);
                }
            #pragma unroll
            for (int ch = 0; ch < 4; ch++) {
                const int c = wv*64 + ch*16 + l16;
                const float bs = bm1[c];
                #pragma unroll
                for (int reg = 0; reg < 4; reg++)
                    D[(quad*4+reg)*DST + c] = elu_(ac[ch][reg] + bs);
            }
        }
        __syncthreads();   // (4) m1o ready

        // m2
        if (tid < 32) {
            int r = tid >> 1, v = tid & 1;
            const float* w = Wm2 + (size_t)v*H;
            float s = bm2[v];
            #pragma unroll 4
            for (int i = 0; i < H/4; i++) {
                float4 a = *(const float4*)&D[r*DST + i*4];
                float4 c = *(const float4*)&w[i*4];
                s = fmaf(a.x,c.x,s); s = fmaf(a.y,c.y,s);
                s = fmaf(a.z,c.z,s); s = fmaf(a.w,c.w,s);
            }
            out[((size_t)act_t*RA + ra0 + r)*NMV + v] = tanh_(s)*STEPSC;
        }
        return;
    }
    b -= FAB;

    // ============ COMBINED fc(fc_t) + gru(gru_t): 8 col-groups, 3 stages ============
    {
        const bool do_gru = (gru_t >= 0);
        const bool do_fc  = (fc_t >= 0);
        if (!do_gru && !do_fc) return;
        _Float16* Bw = (_Float16*)smem;
        const int par = do_gru ? (gru_t & 1) : ((fc_t + 1) & 1);
        const _Float16* hin  = par ? hp1 : hp0;
        _Float16*       hout = par ? hp0 : hp1;            // gru output
        _Float16*       pout = (fc_t & 1) ? proc1 : proc0; // fc output
        const int xm = b % 320, ys = b / 320;              // ys in 0..7
        const int m0 = xm*64 + wv*16;

        // A-frags loaded ONCE, used by both fc and gru
        half8 Ah[8];
        #pragma unroll
        for (int kc = 0; kc < 8; kc++)
            Ah[kc] = *(const half8*)(hin + (size_t)(m0 + l16)*H + quad*8 + kc*32);

        if (do_gru) {
            float xv[4][5];
            #pragma unroll
            for (int r = 0; r < 4; r++) {
                int row = m0 + quad*4 + r;
                float2 ob = *(const float2*)(obs + (size_t)row*2);
                xv[r][0] = ob.x; xv[r][1] = ob.y;
                int bb = row / (AA*EE), e = row % EE;
                const float* pp = phys + (size_t)(bb*EE + e)*3;
                xv[r][2]=pp[0]; xv[r][3]=pp[1]; xv[r][4]=pp[2];
            }
            for (int s = 0; s < 2; s++) {
                const int cs = ys*2 + s;                   // 0..15
                if (s) __syncthreads();
                #pragma unroll
                for (int k = 0; k < 6; k++) {
                    int i = tid + 256*k;
                    int g = i >> 9;
                    cp16(wWhh + (size_t)(g*16+cs)*4096 + (i & 511)*8, &Bw[(size_t)i*8]);
                }
                __syncthreads();

                f32x4 acc[3];
                #pragma unroll
                for (int g = 0; g < 3; g++) acc[g] = (f32x4){0.f,0.f,0.f,0.f};
                #pragma unroll
                for (int kc = 0; kc < 8; kc++)
                    #pragma unroll
                    for (int g = 0; g < 3; g++) {
                        half8 w = *(const half8*)&Bw[(g*8 + kc)*512 + lane*8];
                        acc[g] = MFMA16(Ah[kc], w, acc[g]);
                    }

                const int col = cs*16 + l16;
                const float bhr = bhh[col], bhz = bhh[256+col], bhn = bhh[512+col];
                const float br_ = bih[col], bz_ = bih[256+col], bn_ = bih[512+col];
                const float* pr = Wih + (size_t)col*5;
                const float* pz = Wih + (size_t)(256+col)*5;
                const float* pn = Wih + (size_t)(512+col)*5;
                #pragma unroll
                for (int r = 0; r < 4; r++) {
                    int row = m0 + quad*4 + r;
                    float gr = br_, gz = bz_, gn = bn_;
                    #pragma unroll
                    for (int j = 0; j < 5; j++) {
                        gr = fmaf(xv[r][j], pr[j], gr);
                        gz = fmaf(xv[r][j], pz[j], gz);
                        gn = fmaf(xv[r][j], pn[j], gn);
                    }
                    float rg = sigmoid_(gr + acc[0][r] + bhr);
                    float z  = sigmoid_(gz + acc[1][r] + bhz);
                    float n  = tanh_(gn + rg*(acc[2][r] + bhn));
                    size_t idx = (size_t)row*H + col;
                    float hprev = (float)hin[idx];
                    ntstore_h(hout + idx, (_Float16)((1.f - z)*n + z*hprev));
                }
            }
        }

        if (do_fc) {
            const int cs2 = ys;                            // 0..7, 32 cols
            __syncthreads();           // protect Bw from previous reads
            #pragma unroll
            for (int k = 0; k < 4; k++) {
                int i = tid + 256*k;
                cp16(wWfc + (size_t)cs2*8192 + i*8, &Bw[(size_t)i*8]);
            }
            __syncthreads();

            f32x4 acc[2];
            acc[0] = (f32x4){0.f,0.f,0.f,0.f};
            acc[1] = (f32x4){0.f,0.f,0.f,0.f};
            #pragma unroll
            for (int kc = 0; kc < 8; kc++)
                #pragma unroll
                for (int ni = 0; ni < 2; ni++) {
                    half8 w = *(const half8*)&Bw[ni*4096 + kc*512 + lane*8];
                    acc[ni] = MFMA16(Ah[kc], w, acc[ni]);
                }
            #pragma unroll
            for (int ni = 0; ni < 2; ni++) {
                const int col = cs2*32 + ni*16 + l16;
                const float bs = bfcp[col];
                #pragma unroll
                for (int r = 0; r < 4; r++) {
                    int row = m0 + quad*4 + r;
                    ntstore_h(pout + (size_t)row*H + col, (_Float16)elu_(acc[ni][r] + bs));
                }
            }
        }
    }
}

extern "C" void kernel_launch(void* const* d_in, const int* in_sizes, int n_in,
                              void* d_out, int out_size, void* d_ws, size_t ws_size,
                              hipStream_t stream)
{
    const float* obs  = (const float*)d_in[0];
    const float* phys = (const float*)d_in[1];
    const float* goals= (const float*)d_in[2];
    const float* memp = (const float*)d_in[3];
    const float* mema = (const float*)d_in[4];
    const float* Wihp = (const float*)d_in[5];
    const float* Whhp = (const float*)d_in[6];
    const float* bihp = (const float*)d_in[7];
    const float* bhhp = (const float*)d_in[8];
    const float* Wfcp = (const float*)d_in[9];
    const float* bfcp = (const float*)d_in[10];
    const float* Wiha = (const float*)d_in[11];
    const float* Whha = (const float*)d_in[12];
    const float* biha = (const float*)d_in[13];
    const float* bhha = (const float*)d_in[14];
    const float* Wfca = (const float*)d_in[15];
    const float* bfca = (const float*)d_in[16];
    const float* Wm1  = (const float*)d_in[17];
    const float* bm1  = (const float*)d_in[18];
    const float* Wm2  = (const float*)d_in[19];
    const float* bm2  = (const float*)d_in[20];
    float* out = (float*)d_out;
    (void)ws_size;

    char* base = (char*)d_ws;
    size_t off = 0;
    auto alloc = [&](size_t bytes) -> char* {
        char* p = base + off;
        off += (bytes + 255) & ~(size_t)255;
        return p;
    };
    _Float16* wp_whh = (_Float16*)alloc((size_t)G3*H*2);
    _Float16* wp_wfc = (_Float16*)alloc((size_t)H*H*2);
    _Float16* wa_whh = (_Float16*)alloc((size_t)G3*H*2);
    _Float16* wa_wih = (_Float16*)alloc((size_t)G3*H*2);
    _Float16* wa_wfc = (_Float16*)alloc((size_t)H*H*2);
    _Float16* wa_wm1 = (_Float16*)alloc((size_t)H*H*2);
    _Float16* gia    = (_Float16*)alloc((size_t)RA*G3*2);
    _Float16* hp0    = (_Float16*)alloc((size_t)RP*H*2);
    _Float16* hp1    = (_Float16*)alloc((size_t)RP*H*2);
    _Float16* proc0  = (_Float16*)alloc((size_t)RP*H*2);
    _Float16* proc1  = (_Float16*)alloc((size_t)RP*H*2);
    _Float16* ha0    = (_Float16*)alloc((size_t)RA*H*2);
    _Float16* ha1    = (_Float16*)alloc((size_t)RA*H*2);

    // --- pre-pass ---
    k_splitw<<<(G3*H+255)/256, 256, 0, stream>>>(Whhp, wp_whh, G3*H, H);
    k_splitw<<<(H*H+255)/256, 256, 0, stream>>>(Wfcp, wp_wfc, H*H, H);
    k_splitw<<<(G3*H+255)/256, 256, 0, stream>>>(Whha, wa_whh, G3*H, H);
    k_splitw<<<(G3*H+255)/256, 256, 0, stream>>>(Wiha, wa_wih, G3*H, 259);
    k_splitw<<<(H*H+255)/256, 256, 0, stream>>>(Wfca, wa_wfc, H*H, H);
    k_splitw<<<(H*H+255)/256, 256, 0, stream>>>(Wm1,  wa_wm1, H*H, H);
    k_gia_goal<<<RA*G3/256, 256, 0, stream>>>(goals, Wiha, biha, gia);
    k_cvt<<<((size_t)RP*H+255)/256, 256, 0, stream>>>(memp, hp0, RP*H);
    k_cvt<<<((size_t)RA*H+255)/256, 256, 0, stream>>>(mema, ha0, RA*H);

    // --- 12 pipelined launches: L = {gru(L), fc(L-1), act(L-2)} ---
    const int NB = FAB + COMB;
    for (int L = 0; L <= TT + 1; L++) {
        int gru_t = (L <= TT-1) ? L : -1;
        int fc_t  = (L-1 >= 0 && L-1 <= TT-1) ? L-1 : -1;
        int act_t = (L-2 >= 0 && L-2 <= TT-1) ? L-2 : -1;
        k_step<<<NB, 256, 0, stream>>>(gru_t, fc_t, act_t,
                                       hp0, hp1, proc0, proc1, ha0, ha1,
                                       wp_whh, wp_wfc, wa_whh, wa_wih, wa_wfc, wa_wm1,
                                       gia, obs, phys,
                                       Wihp, bihp, bhhp, bfcp,
                                       bhha, bfca, bm1, Wm2, bm2, out);
    }
}

// Round 15
// 644.035 us; speedup vs baseline: 1.2082x; 1.2082x over previous
//
#include <hip/hip_runtime.h>
#include <math.h>

#define H 256
#define G3 768        // 3*H
#define BB 512
#define AA 4
#define EE 10
#define RP (BB*AA*EE) // 20480 physical rows
#define RA (BB*AA)    // 2048 action rows
#define TT 10
#define NMV 2
#define STEPSC 0.05f
#define DST 260       // act LDS row stride (floats)
#define A1B 128       // act1: pool + action GRU
#define A2B 256       // act2: fc_a (col-split x2)
#define A3B 128       // act3: m1 + m2
#define COMB 1280     // combined fc+gru: 160 row-tiles (128 rows) x 8 col-groups

typedef __attribute__((ext_vector_type(8))) short short8;
typedef __attribute__((ext_vector_type(8))) _Float16 half8;
typedef __attribute__((ext_vector_type(4))) float f32x4;

#if defined(__has_builtin)
#  if __has_builtin(__builtin_amdgcn_global_load_lds)
#    define HAS_GLL 1
#  endif
#endif

__device__ __forceinline__ float sigmoid_(float x){ return 1.f/(1.f + __expf(-x)); }
__device__ __forceinline__ float tanh_(float x){
    float ax = fabsf(x);
    float e  = __expf(-2.f*ax);
    float t  = (1.f - e)/(1.f + e);
    return copysignf(t, x);
}
__device__ __forceinline__ float elu_(float x){ return x > 0.f ? x : (__expf(x) - 1.f); }

#define MFMA16(A,B,C) __builtin_amdgcn_mfma_f32_16x16x32_f16(A,B,C,0,0,0)

__device__ __forceinline__ void cp16(const void* g, void* l) {
#ifdef HAS_GLL
    __builtin_amdgcn_global_load_lds(
        (const __attribute__((address_space(1))) unsigned int*)g,
        (__attribute__((address_space(3))) unsigned int*)l, 16, 0, 0);
#else
    *(short8*)l = *(const short8*)g;
#endif
}

// ---------------------------------------------------------------------------
// fp32 weight [Nout][ldsrc] -> fp16 in MFMA B-fragment order.
// i = ((chunk*8 + kc)*64 + lane)*8 + j ; row = chunk*16+(lane&15),
// k = kc*32 + (lane>>4)*8 + j.  Chunk = 16 output cols x 256 k = 4096 halfs.
// ---------------------------------------------------------------------------
__global__ void k_splitw(const float* __restrict__ src, _Float16* __restrict__ dst,
                         int n, int ldsrc)
{
    int i = blockIdx.x*256 + threadIdx.x;
    if (i < n) {
        int j  = i & 7;
        int l  = (i >> 3) & 63;
        int kc = (i >> 9) & 7;
        int c  = i >> 12;
        int row = c*16 + (l & 15);
        int k   = kc*32 + (l >> 4)*8 + j;
        dst[i] = (_Float16)src[(size_t)row*ldsrc + k];
    }
}

// gia[ra][k] = b_ih_a[k] + sum_{j<3} goals[ra][j]*W_ih_a[k][256+j]  (fp16 out)
__global__ void k_gia_goal(const float* __restrict__ goals,
                           const float* __restrict__ Wiha,
                           const float* __restrict__ biha,
                           _Float16* __restrict__ out)
{
    int idx = blockIdx.x*256 + threadIdx.x;
    int ra = idx / G3, k = idx % G3;
    float g0 = goals[ra*3+0], g1 = goals[ra*3+1], g2 = goals[ra*3+2];
    const float* w = Wiha + (size_t)k*259 + 256;
    out[idx] = (_Float16)(biha[k] + g0*w[0] + g1*w[1] + g2*w[2]);
}

// fp32 -> fp16 convert (state init)
__global__ void k_cvt(const float* __restrict__ src, _Float16* __restrict__ dst, int n)
{
    int i = blockIdx.x*256 + threadIdx.x;
    if (i < n) dst[i] = (_Float16)src[i];
}

// ---------------------------------------------------------------------------
// FUSED STEP KERNEL — 5-stage software pipeline across launches.
//   [0,A1B):        act1(a1_t): pool + action-GRU (ha ping-pong)
//   [A1B,+A2B):     act2(a2_t): fc_a (col-split x2) -> proca ping-pong
//   [A1B+A2B,+A3B): act3(a3_t): m1 + m2 -> out
//   [.., +COMB):    combined fc(fc_t)+gru(gru_t): 128-ROW blocks (2 tiles/wave)
//                   to halve per-launch weight re-read traffic; shared A-frags;
//                   8 col-groups; 2 gru slices + 1 fc slice per block.
// ---------------------------------------------------------------------------
__global__ __launch_bounds__(256, 2)
void k_step(int gru_t, int fc_t, int a1_t, int a2_t, int a3_t,
            _Float16* __restrict__ hp0, _Float16* __restrict__ hp1,
            _Float16* __restrict__ proc0, _Float16* __restrict__ proc1,
            _Float16* __restrict__ ha0, _Float16* __restrict__ ha1,
            _Float16* __restrict__ pca0, _Float16* __restrict__ pca1,
            const _Float16* __restrict__ wWhh, const _Float16* __restrict__ wWfc,
            const _Float16* __restrict__ wWhha, const _Float16* __restrict__ wWiha,
            const _Float16* __restrict__ wWfca, const _Float16* __restrict__ wWm1,
            const _Float16* __restrict__ gia,
            const float* __restrict__ obs, const float* __restrict__ phys,
            const float* __restrict__ Wih, const float* __restrict__ bih,
            const float* __restrict__ bhh, const float* __restrict__ bfcp,
            const float* __restrict__ bhha, const float* __restrict__ bfca,
            const float* __restrict__ bm1,
            const float* __restrict__ Wm2, const float* __restrict__ bm2,
            float* __restrict__ out)
{
    __shared__ char smem[24576];
    int b = blockIdx.x;
    const int tid = threadIdx.x;
    const int wv = tid >> 6, lane = tid & 63;
    const int quad = lane >> 4, l16 = lane & 15;

    // ===================== ACT1: pool + action GRU =====================
    if (b < A1B) {
        if (a1_t < 0) return;
        float* D = (float*)smem;
        const _Float16* proc = (a1_t & 1) ? proc1 : proc0;
        const _Float16* hain = (a1_t & 1) ? ha1 : ha0;
        _Float16*      haout = (a1_t & 1) ? ha0 : ha1;
        const int ra0 = b*16;

        // pool: feat = max_e proc (half8-vectorized)
        for (int i = tid; i < 16*32; i += 256) {
            int r = i >> 5, cg = (i & 31)*8;
            const _Float16* p = proc + ((size_t)(ra0 + r)*EE)*H + cg;
            half8 v = *(const half8*)p;
            float m[8];
            #pragma unroll
            for (int j = 0; j < 8; j++) m[j] = (float)v[j];
            #pragma unroll
            for (int e = 1; e < EE; e++) {
                half8 u = *(const half8*)(p + (size_t)e*H);
                #pragma unroll
                for (int j = 0; j < 8; j++) m[j] = fmaxf(m[j], (float)u[j]);
            }
            #pragma unroll
            for (int j = 0; j < 8; j++) D[r*DST + cg + j] = m[j];
        }
        __syncthreads();

        half8 Fh[8], Hh[8];
        #pragma unroll
        for (int kc = 0; kc < 8; kc++) {
            const float* fp = &D[l16*DST + quad*8 + kc*32];
            #pragma unroll
            for (int j = 0; j < 8; j++) Fh[kc][j] = (_Float16)fp[j];
            Hh[kc] = *(const half8*)(hain + (size_t)(ra0 + l16)*H + quad*8 + kc*32);
        }

        #pragma unroll
        for (int p = 0; p < 2; p++) {
            f32x4 gh[3][2], gx[3][2];
            #pragma unroll
            for (int g = 0; g < 3; g++)
                #pragma unroll
                for (int ch = 0; ch < 2; ch++) {
                    gh[g][ch] = (f32x4){0.f,0.f,0.f,0.f};
                    gx[g][ch] = (f32x4){0.f,0.f,0.f,0.f};
                }
            #pragma unroll
            for (int kc = 0; kc < 8; kc++)
                #pragma unroll
                for (int ch = 0; ch < 2; ch++)
                    #pragma unroll
                    for (int g = 0; g < 3; g++) {
                        const size_t cg = (size_t)(g*16 + wv*4 + p*2 + ch);
                        half8 bh = *(const half8*)(wWhha + (cg*8+kc)*512 + lane*8);
                        half8 bx = *(const half8*)(wWiha + (cg*8+kc)*512 + lane*8);
                        gh[g][ch] = MFMA16(Hh[kc], bh, gh[g][ch]);
                        gx[g][ch] = MFMA16(Fh[kc], bx, gx[g][ch]);
                    }
            #pragma unroll
            for (int ch = 0; ch < 2; ch++) {
                const int c = wv*64 + (p*2+ch)*16 + l16;
                const float br = bhha[c], bz = bhha[256+c], bn = bhha[512+c];
                #pragma unroll
                for (int reg = 0; reg < 4; reg++) {
                    const int r = quad*4 + reg;
                    const _Float16* gp = gia + (size_t)(ra0 + r)*G3;
                    float rg = sigmoid_((float)gp[c]     + gx[0][ch][reg] + gh[0][ch][reg] + br);
                    float z  = sigmoid_((float)gp[256+c] + gx[1][ch][reg] + gh[1][ch][reg] + bz);
                    float n  = tanh_((float)gp[512+c] + gx[2][ch][reg] + rg*(gh[2][ch][reg] + bn));
                    size_t idx = (size_t)(ra0 + r)*H + c;
                    float hprev = (float)hain[idx];
                    haout[idx] = (_Float16)((1.f - z)*n + z*hprev);
                }
            }
        }
        return;
    }
    b -= A1B;

    // ===================== ACT2: fc_a (col-split) =====================
    if (b < A2B) {
        if (a2_t < 0) return;
        const _Float16* hnew = (a2_t & 1) ? ha0 : ha1;   // ha[(t+1)&1]
        _Float16*       pca  = (a2_t & 1) ? pca1 : pca0;
        const int ra0 = (b >> 1)*16;
        const int half = b & 1;

        half8 Hh[8];
        #pragma unroll
        for (int kc = 0; kc < 8; kc++)
            Hh[kc] = *(const half8*)(hnew + (size_t)(ra0 + l16)*H + quad*8 + kc*32);

        f32x4 ac[2];
        ac[0] = (f32x4){0.f,0.f,0.f,0.f};
        ac[1] = (f32x4){0.f,0.f,0.f,0.f};
        #pragma unroll
        for (int kc = 0; kc < 8; kc++)
            #pragma unroll
            for (int ch = 0; ch < 2; ch++) {
                const size_t cidx = (size_t)(half*8 + wv*2 + ch);
                half8 w = *(const half8*)(wWfca + (cidx*8+kc)*512 + lane*8);
                ac[ch] = MFMA16(Hh[kc], w, ac[ch]);
            }
        #pragma unroll
        for (int ch = 0; ch < 2; ch++) {
            const int c = (half*8 + wv*2 + ch)*16 + l16;
            const float bs = bfca[c];
            #pragma unroll
            for (int reg = 0; reg < 4; reg++) {
                int row = ra0 + quad*4 + reg;
                pca[(size_t)row*H + c] = (_Float16)elu_(ac[ch][reg] + bs);
            }
        }
        return;
    }
    b -= A2B;

    // ===================== ACT3: m1 + m2 =====================
    if (b < A3B) {
        if (a3_t < 0) return;
        float* D = (float*)smem;
        const _Float16* pca = (a3_t & 1) ? pca1 : pca0;
        const int ra0 = b*16;

        half8 Ph[8];
        #pragma unroll
        for (int kc = 0; kc < 8; kc++)
            Ph[kc] = *(const half8*)(pca + (size_t)(ra0 + l16)*H + quad*8 + kc*32);

        f32x4 ac[4];
        #pragma unroll
        for (int ch = 0; ch < 4; ch++) ac[ch] = (f32x4){0.f,0.f,0.f,0.f};
        #pragma unroll
        for (int kc = 0; kc < 8; kc++)
            #pragma unroll
            for (int ch = 0; ch < 4; ch++) {
                half8 w = *(const half8*)(wWm1 + ((size_t)(wv*4+ch)*8+kc)*512 + lane*8);
                ac[ch] = MFMA16(Ph[kc], w, ac[ch]);
            }
        #pragma unroll
        for (int ch = 0; ch < 4; ch++) {
            const int c = wv*64 + ch*16 + l16;
            const float bs = bm1[c];
            #pragma unroll
            for (int reg = 0; reg < 4; reg++)
                D[(quad*4+reg)*DST + c] = elu_(ac[ch][reg] + bs);
        }
        __syncthreads();

        if (tid < 32) {
            int r = tid >> 1, v = tid & 1;
            const float* w = Wm2 + (size_t)v*H;
            float s = bm2[v];
            #pragma unroll 4
            for (int i = 0; i < H/4; i++) {
                float4 a = *(const float4*)&D[r*DST + i*4];
                float4 c = *(const float4*)&w[i*4];
                s = fmaf(a.x,c.x,s); s = fmaf(a.y,c.y,s);
                s = fmaf(a.z,c.z,s); s = fmaf(a.w,c.w,s);
            }
            out[((size_t)a3_t*RA + ra0 + r)*NMV + v] = tanh_(s)*STEPSC;
        }
        return;
    }
    b -= A3B;

    // ==== COMBINED fc(fc_t)+gru(gru_t): 128-row blocks, 2 tiles/wave ====
    {
        const bool do_gru = (gru_t >= 0);
        const bool do_fc  = (fc_t >= 0);
        if (!do_gru && !do_fc) return;
        _Float16* Bw = (_Float16*)smem;
        const int par = do_gru ? (gru_t & 1) : ((fc_t + 1) & 1);
        const _Float16* hin  = par ? hp1 : hp0;
        _Float16*       hout = par ? hp0 : hp1;            // gru output
        _Float16*       pout = (fc_t & 1) ? proc1 : proc0; // fc output
        const int xm = b % 160, ys = b / 160;              // ys in 0..7
        const int mt0 = xm*128 + wv*16;                    // tile 0 rows
        const int mt1 = mt0 + 64;                          // tile 1 rows

        // A-frags for both tiles, loaded ONCE, used by gru AND fc
        half8 Ah[2][8];
        #pragma unroll
        for (int kc = 0; kc < 8; kc++) {
            Ah[0][kc] = *(const half8*)(hin + (size_t)(mt0 + l16)*H + quad*8 + kc*32);
            Ah[1][kc] = *(const half8*)(hin + (size_t)(mt1 + l16)*H + quad*8 + kc*32);
        }

        if (do_gru) {
            for (int s = 0; s < 2; s++) {
                const int cs = ys*2 + s;                   // 0..15
                if (s) __syncthreads();
                #pragma unroll
                for (int k = 0; k < 6; k++) {
                    int i = tid + 256*k;
                    int g = i >> 9;
                    cp16(wWhh + (size_t)(g*16+cs)*4096 + (i & 511)*8, &Bw[(size_t)i*8]);
                }
                __syncthreads();

                f32x4 acc[2][3];
                #pragma unroll
                for (int mt = 0; mt < 2; mt++)
                    #pragma unroll
                    for (int g = 0; g < 3; g++) acc[mt][g] = (f32x4){0.f,0.f,0.f,0.f};
                #pragma unroll
                for (int kc = 0; kc < 8; kc++)
                    #pragma unroll
                    for (int g = 0; g < 3; g++) {
                        half8 w = *(const half8*)&Bw[(g*8 + kc)*512 + lane*8];
                        acc[0][g] = MFMA16(Ah[0][kc], w, acc[0][g]);
                        acc[1][g] = MFMA16(Ah[1][kc], w, acc[1][g]);
                    }

                const int col = cs*16 + l16;
                const float bhr = bhh[col], bhz = bhh[256+col], bhn = bhh[512+col];
                const float br_ = bih[col], bz_ = bih[256+col], bn_ = bih[512+col];
                const float* pr = Wih + (size_t)col*5;
                const float* pz = Wih + (size_t)(256+col)*5;
                const float* pn = Wih + (size_t)(512+col)*5;
                #pragma unroll
                for (int mt = 0; mt < 2; mt++) {
                    const int mb = mt ? mt1 : mt0;
                    #pragma unroll
                    for (int r = 0; r < 4; r++) {
                        int row = mb + quad*4 + r;
                        float2 ob = *(const float2*)(obs + (size_t)row*2);
                        int bb = row / (AA*EE), e = row % EE;
                        const float* pp = phys + (size_t)(bb*EE + e)*3;
                        float xv0 = ob.x, xv1 = ob.y, xv2 = pp[0], xv3 = pp[1], xv4 = pp[2];
                        float gr = br_, gz = bz_, gn = bn_;
                        gr = fmaf(xv0,pr[0],gr); gr = fmaf(xv1,pr[1],gr); gr = fmaf(xv2,pr[2],gr);
                        gr = fmaf(xv3,pr[3],gr); gr = fmaf(xv4,pr[4],gr);
                        gz = fmaf(xv0,pz[0],gz); gz = fmaf(xv1,pz[1],gz); gz = fmaf(xv2,pz[2],gz);
                        gz = fmaf(xv3,pz[3],gz); gz = fmaf(xv4,pz[4],gz);
                        gn = fmaf(xv0,pn[0],gn); gn = fmaf(xv1,pn[1],gn); gn = fmaf(xv2,pn[2],gn);
                        gn = fmaf(xv3,pn[3],gn); gn = fmaf(xv4,pn[4],gn);
                        float rg = sigmoid_(gr + acc[mt][0][r] + bhr);
                        float z  = sigmoid_(gz + acc[mt][1][r] + bhz);
                        float n  = tanh_(gn + rg*(acc[mt][2][r] + bhn));
                        size_t idx = (size_t)row*H + col;
                        float hprev = (float)hin[idx];
                        hout[idx] = (_Float16)((1.f - z)*n + z*hprev);
                    }
                }
            }
        }

        if (do_fc) {
            const int cs2 = ys;                            // 0..7, 32 cols
            __syncthreads();           // protect Bw from previous reads
            #pragma unroll
            for (int k = 0; k < 4; k++) {
                int i = tid + 256*k;
                cp16(wWfc + (size_t)cs2*8192 + i*8, &Bw[(size_t)i*8]);
            }
            __syncthreads();

            f32x4 acc[2][2];
            #pragma unroll
            for (int mt = 0; mt < 2; mt++)
                #pragma unroll
                for (int ni = 0; ni < 2; ni++) acc[mt][ni] = (f32x4){0.f,0.f,0.f,0.f};
            #pragma unroll
            for (int kc = 0; kc < 8; kc++)
                #pragma unroll
                for (int ni = 0; ni < 2; ni++) {
                    half8 w = *(const half8*)&Bw[ni*4096 + kc*512 + lane*8];
                    acc[0][ni] = MFMA16(Ah[0][kc], w, acc[0][ni]);
                    acc[1][ni] = MFMA16(Ah[1][kc], w, acc[1][ni]);
                }
            #pragma unroll
            for (int mt = 0; mt < 2; mt++) {
                const int mb = mt ? mt1 : mt0;
                #pragma unroll
                for (int ni = 0; ni < 2; ni++) {
                    const int col = cs2*32 + ni*16 + l16;
                    const float bs = bfcp[col];
                    #pragma unroll
                    for (int r = 0; r < 4; r++) {
                        int row = mb + quad*4 + r;
                        pout[(size_t)row*H + col] = (_Float16)elu_(acc[mt][ni][r] + bs);
                    }
                }
            }
        }
    }
}

extern "C" void kernel_launch(void* const* d_in, const int* in_sizes, int n_in,
                              void* d_out, int out_size, void* d_ws, size_t ws_size,
                              hipStream_t stream)
{
    const float* obs  = (const float*)d_in[0];
    const float* phys = (const float*)d_in[1];
    const float* goals= (const float*)d_in[2];
    const float* memp = (const float*)d_in[3];
    const float* mema = (const float*)d_in[4];
    const float* Wihp = (const float*)d_in[5];
    const float* Whhp = (const float*)d_in[6];
    const float* bihp = (const float*)d_in[7];
    const float* bhhp = (const float*)d_in[8];
    const float* Wfcp = (const float*)d_in[9];
    const float* bfcp = (const float*)d_in[10];
    const float* Wiha = (const float*)d_in[11];
    const float* Whha = (const float*)d_in[12];
    const float* biha = (const float*)d_in[13];
    const float* bhha = (const float*)d_in[14];
    const float* Wfca = (const float*)d_in[15];
    const float* bfca = (const float*)d_in[16];
    const float* Wm1  = (const float*)d_in[17];
    const float* bm1  = (const float*)d_in[18];
    const float* Wm2  = (const float*)d_in[19];
    const float* bm2  = (const float*)d_in[20];
    float* out = (float*)d_out;
    (void)ws_size;

    char* base = (char*)d_ws;
    size_t off = 0;
    auto alloc = [&](size_t bytes) -> char* {
        char* p = base + off;
        off += (bytes + 255) & ~(size_t)255;
        return p;
    };
    _Float16* wp_whh = (_Float16*)alloc((size_t)G3*H*2);
    _Float16* wp_wfc = (_Float16*)alloc((size_t)H*H*2);
    _Float16* wa_whh = (_Float16*)alloc((size_t)G3*H*2);
    _Float16* wa_wih = (_Float16*)alloc((size_t)G3*H*2);
    _Float16* wa_wfc = (_Float16*)alloc((size_t)H*H*2);
    _Float16* wa_wm1 = (_Float16*)alloc((size_t)H*H*2);
    _Float16* gia    = (_Float16*)alloc((size_t)RA*G3*2);
    _Float16* hp0    = (_Float16*)alloc((size_t)RP*H*2);
    _Float16* hp1    = (_Float16*)alloc((size_t)RP*H*2);
    _Float16* proc0  = (_Float16*)alloc((size_t)RP*H*2);
    _Float16* proc1  = (_Float16*)alloc((size_t)RP*H*2);
    _Float16* ha0    = (_Float16*)alloc((size_t)RA*H*2);
    _Float16* ha1    = (_Float16*)alloc((size_t)RA*H*2);
    _Float16* pca0   = (_Float16*)alloc((size_t)RA*H*2);
    _Float16* pca1   = (_Float16*)alloc((size_t)RA*H*2);

    // --- pre-pass ---
    k_splitw<<<(G3*H+255)/256, 256, 0, stream>>>(Whhp, wp_whh, G3*H, H);
    k_splitw<<<(H*H+255)/256, 256, 0, stream>>>(Wfcp, wp_wfc, H*H, H);
    k_splitw<<<(G3*H+255)/256, 256, 0, stream>>>(Whha, wa_whh, G3*H, H);
    k_splitw<<<(G3*H+255)/256, 256, 0, stream>>>(Wiha, wa_wih, G3*H, 259);
    k_splitw<<<(H*H+255)/256, 256, 0, stream>>>(Wfca, wa_wfc, H*H, H);
    k_splitw<<<(H*H+255)/256, 256, 0, stream>>>(Wm1,  wa_wm1, H*H, H);
    k_gia_goal<<<RA*G3/256, 256, 0, stream>>>(goals, Wiha, biha, gia);
    k_cvt<<<((size_t)RP*H+255)/256, 256, 0, stream>>>(memp, hp0, RP*H);
    k_cvt<<<((size_t)RA*H+255)/256, 256, 0, stream>>>(mema, ha0, RA*H);

    // --- 14 pipelined launches: L = {gru(L), fc(L-1), act1(L-2), act2(L-3), act3(L-4)} ---
    const int NB = A1B + A2B + A3B + COMB;
    for (int L = 0; L <= TT + 3; L++) {
        int gru_t = (L <= TT-1) ? L : -1;
        int fc_t  = (L-1 >= 0 && L-1 <= TT-1) ? L-1 : -1;
        int a1_t  = (L-2 >= 0 && L-2 <= TT-1) ? L-2 : -1;
        int a2_t  = (L-3 >= 0 && L-3 <= TT-1) ? L-3 : -1;
        int a3_t  = (L-4 >= 0 && L-4 <= TT-1) ? L-4 : -1;
        k_step<<<NB, 256, 0, stream>>>(gru_t, fc_t, a1_t, a2_t, a3_t,
                                       hp0, hp1, proc0, proc1, ha0, ha1, pca0, pca1,
                                       wp_whh, wp_wfc, wa_whh, wa_wih, wa_wfc, wa_wm1,
                                       gia, obs, phys,
                                       Wihp, bihp, bhhp, bfcp,
                                       bhha, bfca, bm1, Wm2, bm2, out);
    }
}